// Round 1
// baseline (384.223 us; speedup 1.0000x reference)
//
#include <hip/hip_runtime.h>
#include <math.h>

// Problem constants
#define LQ    512
#define DS    384
#define DPAIR 128
#define NH    12
#define NPP   1792   // padded projection width
#define FE    48     // logits feature dim (32 q + 12 pts + 2)
#define TJC   64     // j-chunk for pair kernel
#define NC    8      // number of j-chunks (LQ/TJC)

typedef unsigned short u16;
typedef unsigned int   u32;
typedef __attribute__((ext_vector_type(8))) short bf16x8;  // 8 bf16 in 4 VGPRs
typedef __attribute__((ext_vector_type(4))) float f32x4;

// round-to-nearest-even f32 -> bf16 bits
__device__ inline u16 bf16_rne(float x) {
  u32 u = __float_as_uint(x);
  u32 r = (u + 0x7FFFu + ((u >> 16) & 1u)) >> 16;
  return (u16)r;
}
// split x ~= hi + lo (both bf16); residual ~2^-17 relative
__device__ inline void split_bf16(float x, u16& h, u16& l) {
  u16 hb = bf16_rne(x);
  float hf = __uint_as_float(((u32)hb) << 16);
  h = hb;
  l = bf16_rne(x - hf);
}

// ---------------------------------------------------------------- concat W -> transposed split-bf16 [NPP][DS]
// tiles 0..167: 64x64 transpose+split via LDS; tile 168: bcat + WpbT
__global__ __launch_bounds__(256) void k_concat_wT(
    const float* __restrict__ Wq, const float* __restrict__ Wk,
    const float* __restrict__ Wv, const float* __restrict__ Wqp,
    const float* __restrict__ Wkp, const float* __restrict__ Wvp,
    const float* __restrict__ bq, const float* __restrict__ bk,
    const float* __restrict__ bv, const float* __restrict__ bqp,
    const float* __restrict__ bkp, const float* __restrict__ bvp,
    const float* __restrict__ Wpb,
    u16* __restrict__ Wth, u16* __restrict__ Wtl,
    float* __restrict__ bcat, float* __restrict__ WpbT) {
  int blk = blockIdx.x, t = threadIdx.x;
  if (blk < 168) {
    __shared__ u16 hi[64][66], lo[64][66];   // stride 66 u16 = 33 dwords -> conflict-free
    int kb = blk / 28, cb = blk % 28;
    int k0 = kb * 64, c0 = cb * 64;
    for (int e = t; e < 4096; e += 256) {
      int rr = e >> 6, cc = e & 63;
      int k = k0 + rr, c = c0 + cc;
      float v = 0.f;
      if (c < 384)       v = Wq[k*384 + c];
      else if (c < 768)  v = Wk[k*384 + c-384];
      else if (c < 1152) v = Wv[k*384 + c-768];
      else if (c < 1296) v = Wqp[k*144 + c-1152];
      else if (c < 1440) v = Wkp[k*144 + c-1296];
      else if (c < 1728) v = Wvp[k*288 + c-1440];
      u16 h_, l_; split_bf16(v, h_, l_);
      hi[rr][cc] = h_; lo[rr][cc] = l_;
    }
    __syncthreads();
    for (int e = t; e < 4096; e += 256) {
      int cc = e >> 6, kk = e & 63;
      Wth[(size_t)(c0+cc)*DS + k0 + kk] = hi[kk][cc];
      Wtl[(size_t)(c0+cc)*DS + k0 + kk] = lo[kk][cc];
    }
  } else {
    for (int e = t; e < NPP + NH*DPAIR; e += 256) {
      if (e < NPP) {
        int c = e;
        float v = 0.f;
        if (c < 384)       v = bq[c];
        else if (c < 768)  v = bk[c-384];
        else if (c < 1152) v = bv[c-768];
        else if (c < 1296) v = bqp[c-1152];
        else if (c < 1440) v = bkp[c-1296];
        else if (c < 1728) v = bvp[c-1440];
        bcat[c] = v;
      } else {
        int e2 = e - NPP;
        int k = e2 / NH, h = e2 % NH;
        WpbT[h*DPAIR + k] = Wpb[e2];
      }
    }
  }
}

// ---------------------------------------------------------------- generic transpose + split (for Wo -> [Cc][R])
__global__ __launch_bounds__(256) void k_transpose_split(
    const float* __restrict__ src, u16* __restrict__ dh, u16* __restrict__ dl,
    int R, int Cc) {
  __shared__ u16 hi[64][66], lo[64][66];
  int r0 = blockIdx.x * 64, c0 = blockIdx.y * 64, t = threadIdx.x;
  for (int e = t; e < 4096; e += 256) {
    int rr = e >> 6, cc = e & 63;
    float v = src[(size_t)(r0+rr)*Cc + c0 + cc];
    u16 h_, l_; split_bf16(v, h_, l_);
    hi[rr][cc] = h_; lo[rr][cc] = l_;
  }
  __syncthreads();
  for (int e = t; e < 4096; e += 256) {
    int cc = e >> 6, rr = e & 63;
    dh[(size_t)(c0+cc)*R + r0 + rr] = hi[rr][cc];
    dl[(size_t)(c0+cc)*R + r0 + rr] = lo[rr][cc];
  }
}

// ---------------------------------------------------------------- elementwise split (comb -> bf16 hi/lo), float4 wide
__global__ void k_split4(const float* __restrict__ src, u16* __restrict__ h,
                         u16* __restrict__ l, int n4) {
  int e = blockIdx.x * 256 + threadIdx.x;
  if (e >= n4) return;
  float4 v = ((const float4*)src)[e];
  u16 h0,l0,h1,l1,h2,l2,h3,l3;
  split_bf16(v.x, h0, l0); split_bf16(v.y, h1, l1);
  split_bf16(v.z, h2, l2); split_bf16(v.w, h3, l3);
  uint2 hp, lp;
  hp.x = (u32)h0 | ((u32)h1 << 16); hp.y = (u32)h2 | ((u32)h3 << 16);
  lp.x = (u32)l0 | ((u32)l1 << 16); lp.y = (u32)l2 | ((u32)l3 << 16);
  ((uint2*)h)[e] = hp; ((uint2*)l)[e] = lp;
}

// ---------------------------------------------------------------- layernorm -> split-bf16 output
__global__ __launch_bounds__(128) void k_layernorm(const float* __restrict__ x,
                                                   const float* __restrict__ w,
                                                   const float* __restrict__ b,
                                                   u16* __restrict__ yh,
                                                   u16* __restrict__ yl) {
  __shared__ float red[128];
  __shared__ float s_mu, s_rstd;
  int i = blockIdx.x, t = threadIdx.x;
  float v0 = x[i*DS + t], v1 = x[i*DS + t + 128], v2 = x[i*DS + t + 256];
  red[t] = v0 + v1 + v2; __syncthreads();
  for (int s = 64; s > 0; s >>= 1) { if (t < s) red[t] += red[t+s]; __syncthreads(); }
  if (t == 0) s_mu = red[0] * (1.f/384.f);
  __syncthreads();
  float mu = s_mu;
  float d0 = v0-mu, d1 = v1-mu, d2 = v2-mu;
  red[t] = d0*d0 + d1*d1 + d2*d2; __syncthreads();
  for (int s = 64; s > 0; s >>= 1) { if (t < s) red[t] += red[t+s]; __syncthreads(); }
  if (t == 0) s_rstd = rsqrtf(red[0] * (1.f/384.f) + 1e-5f);
  __syncthreads();
  float r = s_rstd;
  float y0 = d0*r*w[t      ] + b[t      ];
  float y1 = d1*r*w[t + 128] + b[t + 128];
  float y2 = d2*r*w[t + 256] + b[t + 256];
  u16 h_, l_;
  split_bf16(y0, h_, l_); yh[i*DS + t      ] = h_; yl[i*DS + t      ] = l_;
  split_bf16(y1, h_, l_); yh[i*DS + t + 128] = h_; yl[i*DS + t + 128] = l_;
  split_bf16(y2, h_, l_); yh[i*DS + t + 256] = h_; yl[i*DS + t + 256] = l_;
}

// ---------------------------------------------------------------- MFMA GEMM: C[M][N] = A[M][K] @ Bt[N][K]^T
// 3-term compensated bf16 (AhBh + AhBl + AlBh), f32 accumulate -> ~f32 accuracy.
// 64x64 tile, 4 waves (2x2), each wave 32x32 via 2x2 frags of mfma_f32_16x16x32_bf16.
// A-frag:  a[j] = A[i0 + (lane&15)][k0 + 8*(lane>>4) + j]   (16B contiguous)
// B-frag:  b[j] = Bt[j0 + (lane&15)][k0 + 8*(lane>>4) + j]  (16B contiguous)
// C/D:     D[i0 + 4*(lane>>4) + r][j0 + (lane&15)]          (m89-verified mapping)
__global__ __launch_bounds__(256) void k_gemm_mfma(
    const u16* __restrict__ Ah, const u16* __restrict__ Al,
    const u16* __restrict__ Bth, const u16* __restrict__ Btl,
    const float* __restrict__ bias, float* __restrict__ C,
    float* __restrict__ Cpart, int M, int N, int K) {
  int t = threadIdx.x;
  int lane = t & 63, wave = t >> 6;
  int wr = wave >> 1, wc = wave & 1;
  int i0 = blockIdx.y * 64 + wr * 32;
  int j0 = blockIdx.x * 64 + wc * 32;
  int KS = gridDim.z;
  int kper = K / KS;
  size_t kbeg = (size_t)blockIdx.z * kper;
  int lr = lane & 15, lk = (lane >> 4) << 3;

  const u16* a0h = Ah  + (size_t)(i0 + lr) * K + kbeg + lk;
  const u16* a1h = a0h + (size_t)16 * K;
  const u16* a0l = Al  + (size_t)(i0 + lr) * K + kbeg + lk;
  const u16* a1l = a0l + (size_t)16 * K;
  const u16* b0h = Bth + (size_t)(j0 + lr) * K + kbeg + lk;
  const u16* b1h = b0h + (size_t)16 * K;
  const u16* b0l = Btl + (size_t)(j0 + lr) * K + kbeg + lk;
  const u16* b1l = b0l + (size_t)16 * K;

  f32x4 c00 = {0.f,0.f,0.f,0.f}, c01 = c00, c10 = c00, c11 = c00;
  for (int k = 0; k < kper; k += 32) {
    bf16x8 A0h = *(const bf16x8*)(a0h + k);
    bf16x8 A1h = *(const bf16x8*)(a1h + k);
    bf16x8 B0h = *(const bf16x8*)(b0h + k);
    bf16x8 B1h = *(const bf16x8*)(b1h + k);
    bf16x8 A0l = *(const bf16x8*)(a0l + k);
    bf16x8 A1l = *(const bf16x8*)(a1l + k);
    bf16x8 B0l = *(const bf16x8*)(b0l + k);
    bf16x8 B1l = *(const bf16x8*)(b1l + k);
    c00 = __builtin_amdgcn_mfma_f32_16x16x32_bf16(A0h, B0h, c00, 0, 0, 0);
    c01 = __builtin_amdgcn_mfma_f32_16x16x32_bf16(A0h, B1h, c01, 0, 0, 0);
    c10 = __builtin_amdgcn_mfma_f32_16x16x32_bf16(A1h, B0h, c10, 0, 0, 0);
    c11 = __builtin_amdgcn_mfma_f32_16x16x32_bf16(A1h, B1h, c11, 0, 0, 0);
    c00 = __builtin_amdgcn_mfma_f32_16x16x32_bf16(A0h, B0l, c00, 0, 0, 0);
    c01 = __builtin_amdgcn_mfma_f32_16x16x32_bf16(A0h, B1l, c01, 0, 0, 0);
    c10 = __builtin_amdgcn_mfma_f32_16x16x32_bf16(A1h, B0l, c10, 0, 0, 0);
    c11 = __builtin_amdgcn_mfma_f32_16x16x32_bf16(A1h, B1l, c11, 0, 0, 0);
    c00 = __builtin_amdgcn_mfma_f32_16x16x32_bf16(A0l, B0h, c00, 0, 0, 0);
    c01 = __builtin_amdgcn_mfma_f32_16x16x32_bf16(A0l, B1h, c01, 0, 0, 0);
    c10 = __builtin_amdgcn_mfma_f32_16x16x32_bf16(A1l, B0h, c10, 0, 0, 0);
    c11 = __builtin_amdgcn_mfma_f32_16x16x32_bf16(A1l, B1h, c11, 0, 0, 0);
  }

  int orow = (lane >> 4) << 2;
  int col0 = j0 + lr, col1 = j0 + 16 + lr;
  if (KS == 1) {
    float bb0 = bias[col0], bb1 = bias[col1];
    #pragma unroll
    for (int r = 0; r < 4; r++) {
      int row0 = i0 + orow + r, row1 = row0 + 16;
      C[(size_t)row0*N + col0] = c00[r] + bb0;
      C[(size_t)row0*N + col1] = c01[r] + bb1;
      C[(size_t)row1*N + col0] = c10[r] + bb0;
      C[(size_t)row1*N + col1] = c11[r] + bb1;
    }
  } else {
    float* dst = Cpart + (size_t)blockIdx.z * M * N;
    #pragma unroll
    for (int r = 0; r < 4; r++) {
      int row0 = i0 + orow + r, row1 = row0 + 16;
      dst[(size_t)row0*N + col0] = c00[r];
      dst[(size_t)row0*N + col1] = c01[r];
      dst[(size_t)row1*N + col0] = c10[r];
      dst[(size_t)row1*N + col1] = c11[r];
    }
  }
}

__global__ void k_reduce_bias(const float* __restrict__ part, const float* __restrict__ bias,
                              float* __restrict__ out, int MN, int N, int KS) {
  int e = blockIdx.x * 256 + threadIdx.x;
  if (e >= MN) return;
  float s = bias[e % N];
  for (int z = 0; z < KS; z++) s += part[(size_t)z*MN + e];
  out[e] = s;
}

// ---------------------------------------------------------------- fused rotate + feature build
__global__ void k_rotfeat(const float* __restrict__ C1, const float* __restrict__ rot,
                          const float* __restrict__ trans, const float* __restrict__ gamma,
                          const float* __restrict__ w_c, const float* __restrict__ w_l,
                          float* __restrict__ Af, float* __restrict__ Bf,
                          float* __restrict__ vgb) {
  int idx = blockIdx.x * 256 + threadIdx.x;
  if (idx >= LQ*NH) return;
  int h = idx % NH, i = idx / NH;
  float R[9], tr[3];
  #pragma unroll
  for (int r = 0; r < 9; r++) R[r] = rot[(size_t)i*9 + r];
  #pragma unroll
  for (int r = 0; r < 3; r++) tr[r] = trans[(size_t)i*3 + r];

  float s  = w_c[0] * rsqrtf(32.f);
  float gp = gamma[h] * w_l[0];
  float* a  = Af + ((size_t)h*LQ + i)*FE;
  float* bb = Bf + ((size_t)h*LQ + i)*FE;
  const float* q = C1 + (size_t)i*NPP + h*32;
  const float* k = C1 + (size_t)i*NPP + 384 + h*32;
  #pragma unroll 8
  for (int d = 0; d < 32; d++) { a[d] = s*q[d]; bb[d] = k[d]; }

  const float* qp = C1 + (size_t)i*NPP + 1152 + h*12;
  const float* kp = C1 + (size_t)i*NPP + 1296 + h*12;
  float sq = 0.f, sk = 0.f;
  #pragma unroll
  for (int p = 0; p < 4; p++) {
    float x = qp[p*3], y = qp[p*3+1], z = qp[p*3+2];
    #pragma unroll
    for (int r = 0; r < 3; r++) {
      float g = fmaf(R[r*3],x, fmaf(R[r*3+1],y, fmaf(R[r*3+2],z, tr[r])));
      a[32 + p*3 + r] = gp*g;
      sq = fmaf(g,g,sq);
    }
    float xk = kp[p*3], yk = kp[p*3+1], zk = kp[p*3+2];
    #pragma unroll
    for (int r = 0; r < 3; r++) {
      float g = fmaf(R[r*3],xk, fmaf(R[r*3+1],yk, fmaf(R[r*3+2],zk, tr[r])));
      bb[32 + p*3 + r] = g;
      sk = fmaf(g,g,sk);
    }
  }
  a[44] = -0.5f*gp*sq; a[45] = 1.f; a[46] = 0.f; a[47] = 0.f;
  bb[44] = 1.f; bb[45] = -0.5f*gp*sk; bb[46] = 0.f; bb[47] = 0.f;

  const float* vp = C1 + (size_t)i*NPP + 1440 + h*24;
  float* vd = vgb + ((size_t)i*NH + h)*24;
  #pragma unroll
  for (int p = 0; p < 8; p++) {
    float x = vp[p*3], y = vp[p*3+1], z = vp[p*3+2];
    #pragma unroll
    for (int r = 0; r < 3; r++)
      vd[p*3 + r] = fmaf(R[r*3],x, fmaf(R[r*3+1],y, fmaf(R[r*3+2],z, tr[r])));
  }
}

// ---------------------------------------------------------------- batched NT GEMM: S[h] = A_h @ B_h^T  (K=48)
__global__ __launch_bounds__(256) void k_logits_nt(const float* __restrict__ Af,
                                                   const float* __restrict__ Bf,
                                                   float* __restrict__ S) {
  __shared__ float As[48*68];
  __shared__ float Bs[48*68];
  int h = blockIdx.z;
  int i0 = blockIdx.y * 64, j0 = blockIdx.x * 64;
  int t = threadIdx.x;
  int mg = t >> 4, ng = t & 15;
  const float* Ahp = Af + (size_t)h*LQ*FE;
  const float* Bhp = Bf + (size_t)h*LQ*FE;
  for (int e = t; e < 64*48; e += 256) {
    int m = e / 48, k = e % 48;
    As[k*68 + m] = Ahp[(size_t)(i0+m)*FE + k];
    Bs[k*68 + m] = Bhp[(size_t)(j0+m)*FE + k];
  }
  __syncthreads();
  float acc[4][4] = {};
  #pragma unroll 8
  for (int k = 0; k < 48; k++) {
    float4 av = *(const float4*)(As + k*68 + mg*4);
    float4 bv = *(const float4*)(Bs + k*68 + ng*4);
    float a[4] = {av.x, av.y, av.z, av.w};
    float b[4] = {bv.x, bv.y, bv.z, bv.w};
    #pragma unroll
    for (int y = 0; y < 4; y++)
      #pragma unroll
      for (int x = 0; x < 4; x++)
        acc[y][x] = fmaf(a[y], b[x], acc[y][x]);
  }
  #pragma unroll
  for (int y = 0; y < 4; y++) {
    #pragma unroll
    for (int x = 0; x < 4; x++)
      S[((size_t)h*LQ + i0 + mg*4 + y)*LQ + j0 + ng*4 + x] = acc[y][x];
  }
}

// ---------------------------------------------------------------- pair chunk: bias + chunk softmax + partial pair_out
__global__ __launch_bounds__(256, 2) void k_pair_chunk(
    const float* __restrict__ pair, const float* __restrict__ WpbT,
    const float* __restrict__ bpb, const float* __restrict__ mask,
    float* __restrict__ S, float* __restrict__ pairpart, float* __restrict__ msum) {
  __shared__ float tile[TJC*133];
  __shared__ float wt[NH*TJC];
  int i = blockIdx.x, c = blockIdx.y, t = threadIdx.x;
  int j0 = c*TJC;

  const float4* src = (const float4*)(pair + ((size_t)i*LQ + j0)*DPAIR);
  #pragma unroll
  for (int u = 0; u < 8; u++) {
    int e = t + u*256; int row = e >> 5, c4 = e & 31;
    *(float4*)&tile[row*133 + c4*4] = src[e];
  }

  int j = t & 63;
  int hg = __builtin_amdgcn_readfirstlane(t >> 6);
  int h0 = hg*3;
  float l[3];
  #pragma unroll
  for (int q = 0; q < 3; q++)
    l[q] = S[((size_t)(h0+q)*LQ + i)*LQ + j0 + j] + bpb[h0+q];
  bool dead = (mask[i] * mask[j0 + j] <= 0.f);
  __syncthreads();

  {
    const float* w0p = WpbT + (size_t)(h0+0)*DPAIR;
    const float* w1p = WpbT + (size_t)(h0+1)*DPAIR;
    const float* w2p = WpbT + (size_t)(h0+2)*DPAIR;
    float a0 = 0.f, a1 = 0.f, a2 = 0.f;
    #pragma unroll 8
    for (int k = 0; k < DPAIR; k += 4) {
      float4 pv = *(const float4*)&tile[j*133 + k];
      float4 w0 = *(const float4*)(w0p + k);
      float4 w1 = *(const float4*)(w1p + k);
      float4 w2 = *(const float4*)(w2p + k);
      a0 = fmaf(pv.x,w0.x, fmaf(pv.y,w0.y, fmaf(pv.z,w0.z, fmaf(pv.w,w0.w, a0))));
      a1 = fmaf(pv.x,w1.x, fmaf(pv.y,w1.y, fmaf(pv.z,w1.z, fmaf(pv.w,w1.w, a1))));
      a2 = fmaf(pv.x,w2.x, fmaf(pv.y,w2.y, fmaf(pv.z,w2.z, fmaf(pv.w,w2.w, a2))));
    }
    l[0] += a0; l[1] += a1; l[2] += a2;
    if (dead) { l[0] = -1e9f; l[1] = -1e9f; l[2] = -1e9f; }
  }

  #pragma unroll
  for (int q = 0; q < 3; q++) {
    float m = l[q];
    #pragma unroll
    for (int o = 32; o > 0; o >>= 1) m = fmaxf(m, __shfl_xor(m, o, 64));
    float w = __expf(l[q] - m);
    float sm = w;
    #pragma unroll
    for (int o = 32; o > 0; o >>= 1) sm += __shfl_xor(sm, o, 64);
    wt[(h0+q)*TJC + j] = w;
    S[((size_t)(h0+q)*LQ + i)*LQ + j0 + j] = w;
    if (j == 0) {
      float* dst = msum + (((size_t)i*NC + c)*NH + h0 + q)*2;
      dst[0] = m; dst[1] = sm;
    }
  }
  __syncthreads();

  int dg = t & 31, strip = t >> 5, jb = strip*8;
  float4 pv[8];
  #pragma unroll
  for (int q = 0; q < 8; q++) pv[q] = *(const float4*)&tile[(jb+q)*133 + dg*4];
  float4 acc[NH];
  #pragma unroll
  for (int h = 0; h < NH; h++) acc[h] = make_float4(0.f,0.f,0.f,0.f);
  #pragma unroll
  for (int h = 0; h < NH; h++) {
    float4 w0 = *(const float4*)&wt[h*TJC + jb];
    float4 w1 = *(const float4*)&wt[h*TJC + jb + 4];
    float wq[8] = {w0.x,w0.y,w0.z,w0.w,w1.x,w1.y,w1.z,w1.w};
    float4 a = acc[h];
    #pragma unroll
    for (int q = 0; q < 8; q++) {
      a.x = fmaf(wq[q], pv[q].x, a.x);
      a.y = fmaf(wq[q], pv[q].y, a.y);
      a.z = fmaf(wq[q], pv[q].z, a.z);
      a.w = fmaf(wq[q], pv[q].w, a.w);
    }
    acc[h] = a;
  }
  __syncthreads();

  float4* red4 = (float4*)tile;
  float4 tot[2];
  tot[0] = make_float4(0.f,0.f,0.f,0.f);
  tot[1] = make_float4(0.f,0.f,0.f,0.f);
  #pragma unroll
  for (int half = 0; half < 2; half++) {
    if ((strip >> 2) == half) {
      #pragma unroll
      for (int h = 0; h < NH; h++)
        red4[(((strip & 3)*NH) + h)*32 + dg] = acc[h];
    }
    __syncthreads();
    for (int e = t, u = 0; e < NH*32; e += 256, u++) {
      int rh = e >> 5, rd = e & 31;
      #pragma unroll
      for (int s4 = 0; s4 < 4; s4++) {
        float4 v = red4[((s4*NH) + rh)*32 + rd];
        tot[u].x += v.x; tot[u].y += v.y; tot[u].z += v.z; tot[u].w += v.w;
      }
    }
    __syncthreads();
  }
  for (int e = t, u = 0; e < NH*32; e += 256, u++) {
    int rh = e >> 5, rd = e & 31;
    *(float4*)&pairpart[(((size_t)i*NC + c)*NH + rh)*DPAIR + rd*4] = tot[u];
  }
}

// ---------------------------------------------------------------- per-chunk softmax scales + pair_out combine
__global__ __launch_bounds__(384) void k_scs_pairout(
    const float* __restrict__ msum, const float* __restrict__ pairpart,
    float* __restrict__ scs_g, float* __restrict__ comb) {
  __shared__ float scs[NH*NC];
  int i = blockIdx.x, t = threadIdx.x;
  if (t < NH) {
    float m = -3.0e38f;
    float mc[NC], sc_[NC];
    #pragma unroll
    for (int c = 0; c < NC; c++) {
      const float* p = msum + (((size_t)i*NC + c)*NH + t)*2;
      mc[c] = p[0]; sc_[c] = p[1];
      m = fmaxf(m, mc[c]);
    }
    float s = 0.f;
    #pragma unroll
    for (int c = 0; c < NC; c++) s += sc_[c] * __expf(mc[c] - m);
    float inv = 1.f / s;
    #pragma unroll
    for (int c = 0; c < NC; c++) {
      float v = __expf(mc[c] - m) * inv;
      scs[t*NC + c] = v;
      scs_g[((size_t)i*NH + t)*NC + c] = v;
    }
  }
  __syncthreads();
  int h = t >> 5, d = t & 31;
  float4 tot = make_float4(0.f,0.f,0.f,0.f);
  #pragma unroll
  for (int c = 0; c < NC; c++) {
    float sc = scs[h*NC + c];
    float4 v = *(const float4*)&pairpart[(((size_t)i*NC + c)*NH + h)*DPAIR + d*4];
    tot.x = fmaf(v.x, sc, tot.x); tot.y = fmaf(v.y, sc, tot.y);
    tot.z = fmaf(v.z, sc, tot.z); tot.w = fmaf(v.w, sc, tot.w);
  }
  *(float4*)&comb[(size_t)i*2304 + 768 + h*DPAIR + d*4] = tot;
}

// ---------------------------------------------------------------- attn @ [v | vg] per head, split-K=4 -> psum
__global__ __launch_bounds__(256) void k_attn_v(const float* __restrict__ attn,
                                                const float* __restrict__ C1,
                                                const float* __restrict__ vg,
                                                const float* __restrict__ scs,
                                                float* __restrict__ psum) {
  __shared__ float As[64*68];
  __shared__ float Vs[64*68];
  int i0 = blockIdx.x * 64;
  int h = blockIdx.y;
  int z = blockIdx.z;
  int t = threadIdx.x;
  int mg = t >> 4, ng = t & 15;
  float acc[4][4] = {};
  for (int k0 = z*128; k0 < z*128 + 128; k0 += 64) {
    int c = k0 >> 6;
    __syncthreads();
    for (int e = t; e < 64*64; e += 256) {
      int m = e >> 6, j = e & 63;
      float sc = scs[((size_t)(i0+m)*NH + h)*NC + c];
      As[j*68 + m] = attn[((size_t)h*LQ + i0 + m)*LQ + k0 + j] * sc;
    }
    for (int e = t; e < 64*64; e += 256) {
      int j = e >> 6, cc = e & 63;
      float v = 0.f;
      if (cc < 32)      v = C1[(size_t)(k0+j)*NPP + 768 + h*32 + cc];
      else if (cc < 56) v = vg[((size_t)(k0+j)*NH + h)*24 + (cc-32)];
      Vs[j*68 + cc] = v;
    }
    __syncthreads();
    #pragma unroll 4
    for (int j = 0; j < 64; j++) {
      float4 av = *(const float4*)(As + j*68 + mg*4);
      float4 bv = *(const float4*)(Vs + j*68 + ng*4);
      float a[4] = {av.x, av.y, av.z, av.w};
      float b[4] = {bv.x, bv.y, bv.z, bv.w};
      #pragma unroll
      for (int y = 0; y < 4; y++)
        #pragma unroll
        for (int x = 0; x < 4; x++)
          acc[y][x] = fmaf(a[y], b[x], acc[y][x]);
    }
  }
  #pragma unroll
  for (int y = 0; y < 4; y++) {
    int i = i0 + mg*4 + y;
    #pragma unroll
    for (int x = 0; x < 4; x++) {
      int n = ng*4 + x;
      psum[(((size_t)z*LQ + i)*NH + h)*64 + n] = acc[y][x];
    }
  }
}

// ---------------------------------------------------------------- fused av_reduce + pts_feat
__global__ void k_avpts(const float* __restrict__ psum, const float* __restrict__ rot,
                        const float* __restrict__ trans, float* __restrict__ comb) {
  int idx = blockIdx.x * 256 + threadIdx.x;
  if (idx >= LQ*NH*40) return;
  int w = idx % 40; int ih = idx / 40; int h = ih % NH; int i = ih / NH;
  size_t base = ((size_t)i*NH + h)*64;
  if (w < 32) {
    float s = 0.f;
    for (int z = 0; z < 4; z++) s += psum[(size_t)z*LQ*NH*64 + base + w];
    comb[(size_t)i*2304 + h*32 + w] = s;
  } else {
    int p = w - 32;
    float g[3];
    #pragma unroll
    for (int r = 0; r < 3; r++) {
      int n = 32 + p*3 + r;
      float s = 0.f;
      for (int z = 0; z < 4; z++) s += psum[(size_t)z*LQ*NH*64 + base + n];
      g[r] = s;
    }
    const float* R = rot + (size_t)i*9;
    const float* tr = trans + (size_t)i*3;
    float x = g[0]-tr[0], y = g[1]-tr[1], z = g[2]-tr[2];
    float lx = fmaf(R[0],x, fmaf(R[3],y, R[6]*z));
    float ly = fmaf(R[1],x, fmaf(R[4],y, R[7]*z));
    float lz = fmaf(R[2],x, fmaf(R[5],y, R[8]*z));
    float nrm = sqrtf(fmaf(lx,lx, fmaf(ly,ly, lz*lz)));
    float* dst = comb + (size_t)i*2304 + 384 + (h*8 + p)*4;
    dst[0] = nrm; dst[1] = lx; dst[2] = ly; dst[3] = lz;
  }
}

// ================================================================ launcher
extern "C" void kernel_launch(void* const* d_in, const int* in_sizes, int n_in,
                              void* d_out, int out_size, void* d_ws, size_t ws_size,
                              hipStream_t stream) {
  const float* single = (const float*)d_in[0];
  const float* pair   = (const float*)d_in[1];
  const float* rot    = (const float*)d_in[2];
  const float* trans  = (const float*)d_in[3];
  const float* mask   = (const float*)d_in[4];
  const float* ln_w   = (const float*)d_in[5];
  const float* ln_b   = (const float*)d_in[6];
  const float* Wq     = (const float*)d_in[7];
  const float* bq     = (const float*)d_in[8];
  const float* Wk     = (const float*)d_in[9];
  const float* bk     = (const float*)d_in[10];
  const float* Wv     = (const float*)d_in[11];
  const float* bv     = (const float*)d_in[12];
  const float* Wqp    = (const float*)d_in[13];
  const float* bqp    = (const float*)d_in[14];
  const float* Wkp    = (const float*)d_in[15];
  const float* bkp    = (const float*)d_in[16];
  const float* Wvp    = (const float*)d_in[17];
  const float* bvp    = (const float*)d_in[18];
  const float* Wpb    = (const float*)d_in[19];
  const float* bpb    = (const float*)d_in[20];
  const float* Wo     = (const float*)d_in[21];
  const float* bo     = (const float*)d_in[22];
  const float* w_c    = (const float*)d_in[23];
  const float* w_l    = (const float*)d_in[24];
  const float* gamma  = (const float*)d_in[25];
  float* out = (float*)d_out;

  float* p = (float*)d_ws;
  auto alloc = [&](size_t n) { float* r = p; p += n; return r; };
  // bf16 buffers allocated in float units (2 u16 per float); all sizes %4==0 -> 16B alignment kept
  u16* WcatTh = (u16*)alloc((size_t)NPP*DS/2);    // Bt [NPP][DS] hi
  u16* WcatTl = (u16*)alloc((size_t)NPP*DS/2);    // Bt [NPP][DS] lo
  u16* snh    = (u16*)alloc((size_t)LQ*DS/2);     // A  [LQ][DS] hi
  u16* snl    = (u16*)alloc((size_t)LQ*DS/2);
  u16* WoTh   = (u16*)alloc((size_t)DS*2304/2);   // Bt [DS][2304] hi
  u16* WoTl   = (u16*)alloc((size_t)DS*2304/2);
  u16* combh  = (u16*)alloc((size_t)LQ*2304/2);   // A  [LQ][2304] hi
  u16* combl  = (u16*)alloc((size_t)LQ*2304/2);
  float* bcat    = alloc(NPP);
  float* WpbT    = alloc((size_t)NH*DPAIR);
  float* C1      = alloc((size_t)LQ*NPP);
  float* vgb     = alloc((size_t)LQ*NH*24);
  float* Af      = alloc((size_t)NH*LQ*FE);
  float* Bf      = alloc((size_t)NH*LQ*FE);
  float* S       = alloc((size_t)NH*LQ*LQ);
  float* pairpart= alloc((size_t)LQ*NC*NH*DPAIR);
  float* msum    = alloc((size_t)LQ*NC*NH*2);
  float* scs_g   = alloc((size_t)LQ*NH*NC);
  float* comb    = alloc((size_t)LQ*2304);
  float* scratch = alloc((size_t)2*LQ*NPP);  // psum (4*512*768) and out partials (8*512*384)

  k_concat_wT<<<dim3(169), 256, 0, stream>>>(
      Wq, Wk, Wv, Wqp, Wkp, Wvp, bq, bk, bv, bqp, bkp, bvp, Wpb,
      WcatTh, WcatTl, bcat, WpbT);
  k_transpose_split<<<dim3(2304/64, DS/64), 256, 0, stream>>>(Wo, WoTh, WoTl, 2304, DS);
  k_layernorm<<<dim3(LQ), 128, 0, stream>>>(single, ln_w, ln_b, snh, snl);
  // proj: C1[LQ][NPP] = sn @ Wcat + bcat, single pass (no split-K round trip)
  k_gemm_mfma<<<dim3(NPP/64, LQ/64, 1), 256, 0, stream>>>(
      snh, snl, WcatTh, WcatTl, bcat, C1, nullptr, LQ, NPP, DS);
  k_rotfeat<<<dim3((LQ*NH + 255)/256), 256, 0, stream>>>(C1, rot, trans, gamma, w_c, w_l, Af, Bf, vgb);
  k_logits_nt<<<dim3(LQ/64, LQ/64, NH), 256, 0, stream>>>(Af, Bf, S);
  k_pair_chunk<<<dim3(LQ, NC), 256, 0, stream>>>(pair, WpbT, bpb, mask, S, pairpart, msum);
  k_scs_pairout<<<dim3(LQ), 384, 0, stream>>>(msum, pairpart, scs_g, comb);
  k_attn_v<<<dim3(LQ/64, NH, 4), 256, 0, stream>>>(S, C1, vgb, scs_g, scratch);
  k_avpts<<<dim3((LQ*NH*40 + 255)/256), 256, 0, stream>>>(scratch, rot, trans, comb);
  k_split4<<<dim3((LQ*2304/4 + 255)/256), 256, 0, stream>>>(comb, combh, combl, LQ*2304/4);
  // out: split-K=8 over K=2304 -> partials in scratch (psum already consumed)
  k_gemm_mfma<<<dim3(DS/64, LQ/64, 8), 256, 0, stream>>>(
      combh, combl, WoTh, WoTl, nullptr, nullptr, scratch, LQ, DS, 2304);
  k_reduce_bias<<<dim3((LQ*DS + 255)/256), 256, 0, stream>>>(scratch, bo, out, LQ*DS, DS, 8);
}

// Round 2
// 366.253 us; speedup vs baseline: 1.0491x; 1.0491x over previous
//
#include <hip/hip_runtime.h>
#include <math.h>

// Problem constants
#define LQ    512
#define DS    384
#define DPAIR 128
#define NH    12
#define NPP   1792   // padded projection width
#define FE2   64     // padded logits feature dim (48 used)
#define TJC   64     // j-chunk for pair kernel
#define NC    8      // number of j-chunks (LQ/TJC)

typedef unsigned short u16;
typedef unsigned int   u32;
typedef __attribute__((ext_vector_type(8))) short bf16x8;  // 8 bf16 in 4 VGPRs
typedef __attribute__((ext_vector_type(4))) float f32x4;

// round-to-nearest-even f32 -> bf16 bits
__device__ inline u16 bf16_rne(float x) {
  u32 u = __float_as_uint(x);
  u32 r = (u + 0x7FFFu + ((u >> 16) & 1u)) >> 16;
  return (u16)r;
}
// split x ~= hi + lo (both bf16); residual ~2^-17 relative
__device__ inline void split_bf16(float x, u16& h, u16& l) {
  u16 hb = bf16_rne(x);
  float hf = __uint_as_float(((u32)hb) << 16);
  h = hb;
  l = bf16_rne(x - hf);
}

// ---------------------------------------------------------------- fused prep:
// blocks 0..167   : Wcat transpose+split tiles -> WcatT [NPP][DS] bf16 hi/lo
// block  168      : bcat + WpbT
// blocks 169..384 : Wo transpose+split tiles   -> WoT [384][2304] bf16 hi/lo
// blocks 385..896 : layernorm rows -> sn split-bf16
__global__ __launch_bounds__(256) void k_prep(
    const float* __restrict__ Wq, const float* __restrict__ Wk,
    const float* __restrict__ Wv, const float* __restrict__ Wqp,
    const float* __restrict__ Wkp, const float* __restrict__ Wvp,
    const float* __restrict__ bq, const float* __restrict__ bk,
    const float* __restrict__ bv, const float* __restrict__ bqp,
    const float* __restrict__ bkp, const float* __restrict__ bvp,
    const float* __restrict__ Wpb, const float* __restrict__ Wo,
    const float* __restrict__ xs, const float* __restrict__ ln_w,
    const float* __restrict__ ln_b,
    u16* __restrict__ Wth, u16* __restrict__ Wtl,
    float* __restrict__ bcat, float* __restrict__ WpbT,
    u16* __restrict__ WoTh, u16* __restrict__ WoTl,
    u16* __restrict__ snh, u16* __restrict__ snl) {
  __shared__ u16 sh_hi[64][66], sh_lo[64][66];   // stride 66 -> conflict-free
  int blk = blockIdx.x, t = threadIdx.x;
  if (blk < 168) {
    int kb = blk / 28, cb = blk % 28;
    int k0 = kb * 64, c0 = cb * 64;
    for (int e = t; e < 4096; e += 256) {
      int rr = e >> 6, cc = e & 63;
      int k = k0 + rr, c = c0 + cc;
      float v = 0.f;
      if (c < 384)       v = Wq[k*384 + c];
      else if (c < 768)  v = Wk[k*384 + c-384];
      else if (c < 1152) v = Wv[k*384 + c-768];
      else if (c < 1296) v = Wqp[k*144 + c-1152];
      else if (c < 1440) v = Wkp[k*144 + c-1296];
      else if (c < 1728) v = Wvp[k*288 + c-1440];
      u16 h_, l_; split_bf16(v, h_, l_);
      sh_hi[rr][cc] = h_; sh_lo[rr][cc] = l_;
    }
    __syncthreads();
    for (int e = t; e < 4096; e += 256) {
      int cc = e >> 6, kk = e & 63;
      Wth[(size_t)(c0+cc)*DS + k0 + kk] = sh_hi[kk][cc];
      Wtl[(size_t)(c0+cc)*DS + k0 + kk] = sh_lo[kk][cc];
    }
  } else if (blk == 168) {
    for (int e = t; e < NPP + NH*DPAIR; e += 256) {
      if (e < NPP) {
        int c = e;
        float v = 0.f;
        if (c < 384)       v = bq[c];
        else if (c < 768)  v = bk[c-384];
        else if (c < 1152) v = bv[c-768];
        else if (c < 1296) v = bqp[c-1152];
        else if (c < 1440) v = bkp[c-1296];
        else if (c < 1728) v = bvp[c-1440];
        bcat[c] = v;
      } else {
        int e2 = e - NPP;
        int k = e2 / NH, h = e2 % NH;
        WpbT[h*DPAIR + k] = Wpb[e2];
      }
    }
  } else if (blk < 385) {
    int idx = blk - 169;
    int kt = idx % 36, nt = idx / 36;      // Wo is [2304][384]
    int k0 = kt * 64, n0 = nt * 64;
    for (int e = t; e < 4096; e += 256) {
      int rr = e >> 6, cc = e & 63;
      float v = Wo[(size_t)(k0+rr)*384 + n0 + cc];
      u16 h_, l_; split_bf16(v, h_, l_);
      sh_hi[rr][cc] = h_; sh_lo[rr][cc] = l_;
    }
    __syncthreads();
    for (int e = t; e < 4096; e += 256) {
      int cc = e >> 6, kk = e & 63;
      WoTh[(size_t)(n0+cc)*2304 + k0 + kk] = sh_hi[kk][cc];
      WoTl[(size_t)(n0+cc)*2304 + k0 + kk] = sh_lo[kk][cc];
    }
  } else {
    // layernorm row, 256 threads covering 384 elements
    int i = blk - 385;
    float* red = (float*)&sh_hi[0][0];
    float a0 = xs[i*DS + t];
    float a1 = (t < 128) ? xs[i*DS + 256 + t] : 0.f;
    red[t] = a0 + a1; __syncthreads();
    for (int s = 128; s > 0; s >>= 1) { if (t < s) red[t] += red[t+s]; __syncthreads(); }
    float mu = red[0] * (1.f/384.f);
    __syncthreads();
    float d0 = a0 - mu, d1 = (t < 128) ? (a1 - mu) : 0.f;
    red[t] = d0*d0 + d1*d1; __syncthreads();
    for (int s = 128; s > 0; s >>= 1) { if (t < s) red[t] += red[t+s]; __syncthreads(); }
    float rstd = rsqrtf(red[0] * (1.f/384.f) + 1e-5f);
    u16 h_, l_;
    float y0 = d0*rstd*ln_w[t] + ln_b[t];
    split_bf16(y0, h_, l_); snh[i*DS + t] = h_; snl[i*DS + t] = l_;
    if (t < 128) {
      float y1 = d1*rstd*ln_w[256+t] + ln_b[256+t];
      split_bf16(y1, h_, l_); snh[i*DS + 256 + t] = h_; snl[i*DS + 256 + t] = l_;
    }
  }
}

// ---------------------------------------------------------------- MFMA GEMM: C[M][N] = A[M][K] @ Bt[N][K]^T
// 3-term compensated bf16 (AhBh + AhBl + AlBh), f32 accumulate -> ~f32 accuracy.
// 64x64 tile, 4 waves (2x2), each wave 32x32 via 2x2 frags of mfma_f32_16x16x32_bf16.
__global__ __launch_bounds__(256) void k_gemm_mfma(
    const u16* __restrict__ Ah, const u16* __restrict__ Al,
    const u16* __restrict__ Bth, const u16* __restrict__ Btl,
    const float* __restrict__ bias, float* __restrict__ C,
    float* __restrict__ Cpart, int M, int N, int K) {
  int t = threadIdx.x;
  int lane = t & 63, wave = t >> 6;
  int wr = wave >> 1, wc = wave & 1;
  int i0 = blockIdx.y * 64 + wr * 32;
  int j0 = blockIdx.x * 64 + wc * 32;
  int KS = gridDim.z;
  int kper = K / KS;
  size_t kbeg = (size_t)blockIdx.z * kper;
  int lr = lane & 15, lk = (lane >> 4) << 3;

  const u16* a0h = Ah  + (size_t)(i0 + lr) * K + kbeg + lk;
  const u16* a1h = a0h + (size_t)16 * K;
  const u16* a0l = Al  + (size_t)(i0 + lr) * K + kbeg + lk;
  const u16* a1l = a0l + (size_t)16 * K;
  const u16* b0h = Bth + (size_t)(j0 + lr) * K + kbeg + lk;
  const u16* b1h = b0h + (size_t)16 * K;
  const u16* b0l = Btl + (size_t)(j0 + lr) * K + kbeg + lk;
  const u16* b1l = b0l + (size_t)16 * K;

  f32x4 c00 = {0.f,0.f,0.f,0.f}, c01 = c00, c10 = c00, c11 = c00;
  for (int k = 0; k < kper; k += 32) {
    bf16x8 A0h = *(const bf16x8*)(a0h + k);
    bf16x8 A1h = *(const bf16x8*)(a1h + k);
    bf16x8 B0h = *(const bf16x8*)(b0h + k);
    bf16x8 B1h = *(const bf16x8*)(b1h + k);
    bf16x8 A0l = *(const bf16x8*)(a0l + k);
    bf16x8 A1l = *(const bf16x8*)(a1l + k);
    bf16x8 B0l = *(const bf16x8*)(b0l + k);
    bf16x8 B1l = *(const bf16x8*)(b1l + k);
    c00 = __builtin_amdgcn_mfma_f32_16x16x32_bf16(A0h, B0h, c00, 0, 0, 0);
    c01 = __builtin_amdgcn_mfma_f32_16x16x32_bf16(A0h, B1h, c01, 0, 0, 0);
    c10 = __builtin_amdgcn_mfma_f32_16x16x32_bf16(A1h, B0h, c10, 0, 0, 0);
    c11 = __builtin_amdgcn_mfma_f32_16x16x32_bf16(A1h, B1h, c11, 0, 0, 0);
    c00 = __builtin_amdgcn_mfma_f32_16x16x32_bf16(A0h, B0l, c00, 0, 0, 0);
    c01 = __builtin_amdgcn_mfma_f32_16x16x32_bf16(A0h, B1l, c01, 0, 0, 0);
    c10 = __builtin_amdgcn_mfma_f32_16x16x32_bf16(A1h, B0l, c10, 0, 0, 0);
    c11 = __builtin_amdgcn_mfma_f32_16x16x32_bf16(A1h, B1l, c11, 0, 0, 0);
    c00 = __builtin_amdgcn_mfma_f32_16x16x32_bf16(A0l, B0h, c00, 0, 0, 0);
    c01 = __builtin_amdgcn_mfma_f32_16x16x32_bf16(A0l, B1h, c01, 0, 0, 0);
    c10 = __builtin_amdgcn_mfma_f32_16x16x32_bf16(A1l, B0h, c10, 0, 0, 0);
    c11 = __builtin_amdgcn_mfma_f32_16x16x32_bf16(A1l, B1h, c11, 0, 0, 0);
  }

  int orow = (lane >> 4) << 2;
  int col0 = j0 + lr, col1 = j0 + 16 + lr;
  if (KS == 1) {
    float bb0 = bias[col0], bb1 = bias[col1];
    #pragma unroll
    for (int r = 0; r < 4; r++) {
      int row0 = i0 + orow + r, row1 = row0 + 16;
      C[(size_t)row0*N + col0] = c00[r] + bb0;
      C[(size_t)row0*N + col1] = c01[r] + bb1;
      C[(size_t)row1*N + col0] = c10[r] + bb0;
      C[(size_t)row1*N + col1] = c11[r] + bb1;
    }
  } else {
    float* dst = Cpart + (size_t)blockIdx.z * M * N;
    #pragma unroll
    for (int r = 0; r < 4; r++) {
      int row0 = i0 + orow + r, row1 = row0 + 16;
      dst[(size_t)row0*N + col0] = c00[r];
      dst[(size_t)row0*N + col1] = c01[r];
      dst[(size_t)row1*N + col0] = c10[r];
      dst[(size_t)row1*N + col1] = c11[r];
    }
  }
}

__global__ void k_reduce_bias(const float* __restrict__ part, const float* __restrict__ bias,
                              float* __restrict__ out, int MN, int N, int KS) {
  int e = blockIdx.x * 256 + threadIdx.x;
  if (e >= MN) return;
  float s = bias[e % N];
  for (int z = 0; z < KS; z++) s += part[(size_t)z*MN + e];
  out[e] = s;
}

// ---------------------------------------------------------------- fused rotate + feature build (split-bf16 outputs)
// Af/Bf: [NH][LQ][FE2] hi/lo (cols 48..63 zero). Vt: [NH][64][LQ] hi/lo
// (rows 0..31 = v, 32..55 = rotated vg, 56..63 zero) = B^T for attn MFMA.
__global__ void k_rotfeat(const float* __restrict__ C1, const float* __restrict__ rot,
                          const float* __restrict__ trans, const float* __restrict__ gamma,
                          const float* __restrict__ w_c, const float* __restrict__ w_l,
                          u16* __restrict__ Afh, u16* __restrict__ Afl,
                          u16* __restrict__ Bfh, u16* __restrict__ Bfl,
                          u16* __restrict__ Vth, u16* __restrict__ Vtl) {
  int idx = blockIdx.x * 256 + threadIdx.x;
  if (idx >= LQ*NH) return;
  int h = idx % NH, i = idx / NH;
  float R[9], tr[3];
  #pragma unroll
  for (int r = 0; r < 9; r++) R[r] = rot[(size_t)i*9 + r];
  #pragma unroll
  for (int r = 0; r < 3; r++) tr[r] = trans[(size_t)i*3 + r];

  float s  = w_c[0] * rsqrtf(32.f);
  float gp = gamma[h] * w_l[0];
  size_t ab = ((size_t)h*LQ + i)*FE2;
  const float* q = C1 + (size_t)i*NPP + h*32;
  const float* k = C1 + (size_t)i*NPP + 384 + h*32;
  u16 h_, l_;
  #pragma unroll 8
  for (int d = 0; d < 32; d++) {
    split_bf16(s*q[d], h_, l_); Afh[ab+d] = h_; Afl[ab+d] = l_;
    split_bf16(k[d],   h_, l_); Bfh[ab+d] = h_; Bfl[ab+d] = l_;
  }

  const float* qp = C1 + (size_t)i*NPP + 1152 + h*12;
  const float* kp = C1 + (size_t)i*NPP + 1296 + h*12;
  float sq = 0.f, sk = 0.f;
  #pragma unroll
  for (int p = 0; p < 4; p++) {
    float x = qp[p*3], y = qp[p*3+1], z = qp[p*3+2];
    #pragma unroll
    for (int r = 0; r < 3; r++) {
      float g = fmaf(R[r*3],x, fmaf(R[r*3+1],y, fmaf(R[r*3+2],z, tr[r])));
      split_bf16(gp*g, h_, l_); Afh[ab+32+p*3+r] = h_; Afl[ab+32+p*3+r] = l_;
      sq = fmaf(g,g,sq);
    }
    float xk = kp[p*3], yk = kp[p*3+1], zk = kp[p*3+2];
    #pragma unroll
    for (int r = 0; r < 3; r++) {
      float g = fmaf(R[r*3],xk, fmaf(R[r*3+1],yk, fmaf(R[r*3+2],zk, tr[r])));
      split_bf16(g, h_, l_); Bfh[ab+32+p*3+r] = h_; Bfl[ab+32+p*3+r] = l_;
      sk = fmaf(g,g,sk);
    }
  }
  split_bf16(-0.5f*gp*sq, h_, l_); Afh[ab+44] = h_; Afl[ab+44] = l_;
  split_bf16(1.f, h_, l_);         Afh[ab+45] = h_; Afl[ab+45] = l_;
  split_bf16(1.f, h_, l_);         Bfh[ab+44] = h_; Bfl[ab+44] = l_;
  split_bf16(-0.5f*gp*sk, h_, l_); Bfh[ab+45] = h_; Bfl[ab+45] = l_;
  #pragma unroll
  for (int d = 46; d < FE2; d++) {
    Afh[ab+d] = 0; Afl[ab+d] = 0; Bfh[ab+d] = 0; Bfl[ab+d] = 0;
  }

  // Vt columns (j = i): v rows then rotated vg rows then zero pad
  const float* vp = C1 + (size_t)i*NPP + 1440 + h*24;
  #pragma unroll 8
  for (int n = 0; n < 32; n++) {
    split_bf16(C1[(size_t)i*NPP + 768 + h*32 + n], h_, l_);
    Vth[((size_t)h*64 + n)*LQ + i] = h_; Vtl[((size_t)h*64 + n)*LQ + i] = l_;
  }
  #pragma unroll
  for (int p = 0; p < 8; p++) {
    float x = vp[p*3], y = vp[p*3+1], z = vp[p*3+2];
    #pragma unroll
    for (int r = 0; r < 3; r++) {
      float g = fmaf(R[r*3],x, fmaf(R[r*3+1],y, fmaf(R[r*3+2],z, tr[r])));
      split_bf16(g, h_, l_);
      Vth[((size_t)h*64 + 32 + p*3 + r)*LQ + i] = h_;
      Vtl[((size_t)h*64 + 32 + p*3 + r)*LQ + i] = l_;
    }
  }
  #pragma unroll
  for (int n = 56; n < 64; n++) {
    Vth[((size_t)h*64 + n)*LQ + i] = 0; Vtl[((size_t)h*64 + n)*LQ + i] = 0;
  }
}

// ---------------------------------------------------------------- logits via MFMA: S[h] = Af_h @ Bf_h^T (K=64)
__global__ __launch_bounds__(256) void k_logits_mfma(
    const u16* __restrict__ Afh, const u16* __restrict__ Afl,
    const u16* __restrict__ Bfh, const u16* __restrict__ Bfl,
    float* __restrict__ S) {
  int t = threadIdx.x;
  int lane = t & 63, wave = t >> 6;
  int wr = wave >> 1, wc = wave & 1;
  int h = blockIdx.z;
  int i0 = blockIdx.y * 64 + wr * 32;
  int j0 = blockIdx.x * 64 + wc * 32;
  int lr = lane & 15, lk = (lane >> 4) << 3;

  const u16* a0h = Afh + ((size_t)h*LQ + i0 + lr)*FE2 + lk;
  const u16* a1h = a0h + (size_t)16*FE2;
  const u16* a0l = Afl + ((size_t)h*LQ + i0 + lr)*FE2 + lk;
  const u16* a1l = a0l + (size_t)16*FE2;
  const u16* b0h = Bfh + ((size_t)h*LQ + j0 + lr)*FE2 + lk;
  const u16* b1h = b0h + (size_t)16*FE2;
  const u16* b0l = Bfl + ((size_t)h*LQ + j0 + lr)*FE2 + lk;
  const u16* b1l = b0l + (size_t)16*FE2;

  f32x4 c00 = {0.f,0.f,0.f,0.f}, c01 = c00, c10 = c00, c11 = c00;
  #pragma unroll
  for (int k = 0; k < FE2; k += 32) {
    bf16x8 A0h = *(const bf16x8*)(a0h + k);
    bf16x8 A1h = *(const bf16x8*)(a1h + k);
    bf16x8 B0h = *(const bf16x8*)(b0h + k);
    bf16x8 B1h = *(const bf16x8*)(b1h + k);
    bf16x8 A0l = *(const bf16x8*)(a0l + k);
    bf16x8 A1l = *(const bf16x8*)(a1l + k);
    bf16x8 B0l = *(const bf16x8*)(b0l + k);
    bf16x8 B1l = *(const bf16x8*)(b1l + k);
    c00 = __builtin_amdgcn_mfma_f32_16x16x32_bf16(A0h, B0h, c00, 0, 0, 0);
    c01 = __builtin_amdgcn_mfma_f32_16x16x32_bf16(A0h, B1h, c01, 0, 0, 0);
    c10 = __builtin_amdgcn_mfma_f32_16x16x32_bf16(A1h, B0h, c10, 0, 0, 0);
    c11 = __builtin_amdgcn_mfma_f32_16x16x32_bf16(A1h, B1h, c11, 0, 0, 0);
    c00 = __builtin_amdgcn_mfma_f32_16x16x32_bf16(A0h, B0l, c00, 0, 0, 0);
    c01 = __builtin_amdgcn_mfma_f32_16x16x32_bf16(A0h, B1l, c01, 0, 0, 0);
    c10 = __builtin_amdgcn_mfma_f32_16x16x32_bf16(A1h, B0l, c10, 0, 0, 0);
    c11 = __builtin_amdgcn_mfma_f32_16x16x32_bf16(A1h, B1l, c11, 0, 0, 0);
    c00 = __builtin_amdgcn_mfma_f32_16x16x32_bf16(A0l, B0h, c00, 0, 0, 0);
    c01 = __builtin_amdgcn_mfma_f32_16x16x32_bf16(A0l, B1h, c01, 0, 0, 0);
    c10 = __builtin_amdgcn_mfma_f32_16x16x32_bf16(A1l, B0h, c10, 0, 0, 0);
    c11 = __builtin_amdgcn_mfma_f32_16x16x32_bf16(A1l, B1h, c11, 0, 0, 0);
  }

  int orow = (lane >> 4) << 2;
  int col0 = j0 + lr, col1 = j0 + 16 + lr;
  #pragma unroll
  for (int r = 0; r < 4; r++) {
    int row0 = i0 + orow + r, row1 = row0 + 16;
    S[((size_t)h*LQ + row0)*LQ + col0] = c00[r];
    S[((size_t)h*LQ + row0)*LQ + col1] = c01[r];
    S[((size_t)h*LQ + row1)*LQ + col0] = c10[r];
    S[((size_t)h*LQ + row1)*LQ + col1] = c11[r];
  }
}

// ---------------------------------------------------------------- pair chunk: bias + chunk softmax + partial pair_out
__global__ __launch_bounds__(256, 2) void k_pair_chunk(
    const float* __restrict__ pair, const float* __restrict__ WpbT,
    const float* __restrict__ bpb, const float* __restrict__ mask,
    float* __restrict__ S, float* __restrict__ pairpart, float* __restrict__ msum) {
  __shared__ float tile[TJC*133];
  __shared__ float wt[NH*TJC];
  int i = blockIdx.x, c = blockIdx.y, t = threadIdx.x;
  int j0 = c*TJC;

  const float4* src = (const float4*)(pair + ((size_t)i*LQ + j0)*DPAIR);
  #pragma unroll
  for (int u = 0; u < 8; u++) {
    int e = t + u*256; int row = e >> 5, c4 = e & 31;
    *(float4*)&tile[row*133 + c4*4] = src[e];
  }

  int j = t & 63;
  int hg = __builtin_amdgcn_readfirstlane(t >> 6);
  int h0 = hg*3;
  float l[3];
  #pragma unroll
  for (int q = 0; q < 3; q++)
    l[q] = S[((size_t)(h0+q)*LQ + i)*LQ + j0 + j] + bpb[h0+q];
  bool dead = (mask[i] * mask[j0 + j] <= 0.f);
  __syncthreads();

  {
    const float* w0p = WpbT + (size_t)(h0+0)*DPAIR;
    const float* w1p = WpbT + (size_t)(h0+1)*DPAIR;
    const float* w2p = WpbT + (size_t)(h0+2)*DPAIR;
    float a0 = 0.f, a1 = 0.f, a2 = 0.f;
    #pragma unroll 8
    for (int k = 0; k < DPAIR; k += 4) {
      float4 pv = *(const float4*)&tile[j*133 + k];
      float4 w0 = *(const float4*)(w0p + k);
      float4 w1 = *(const float4*)(w1p + k);
      float4 w2 = *(const float4*)(w2p + k);
      a0 = fmaf(pv.x,w0.x, fmaf(pv.y,w0.y, fmaf(pv.z,w0.z, fmaf(pv.w,w0.w, a0))));
      a1 = fmaf(pv.x,w1.x, fmaf(pv.y,w1.y, fmaf(pv.z,w1.z, fmaf(pv.w,w1.w, a1))));
      a2 = fmaf(pv.x,w2.x, fmaf(pv.y,w2.y, fmaf(pv.z,w2.z, fmaf(pv.w,w2.w, a2))));
    }
    l[0] += a0; l[1] += a1; l[2] += a2;
    if (dead) { l[0] = -1e9f; l[1] = -1e9f; l[2] = -1e9f; }
  }

  #pragma unroll
  for (int q = 0; q < 3; q++) {
    float m = l[q];
    #pragma unroll
    for (int o = 32; o > 0; o >>= 1) m = fmaxf(m, __shfl_xor(m, o, 64));
    float w = __expf(l[q] - m);
    float sm = w;
    #pragma unroll
    for (int o = 32; o > 0; o >>= 1) sm += __shfl_xor(sm, o, 64);
    wt[(h0+q)*TJC + j] = w;
    S[((size_t)(h0+q)*LQ + i)*LQ + j0 + j] = w;
    if (j == 0) {
      float* dst = msum + (((size_t)i*NC + c)*NH + h0 + q)*2;
      dst[0] = m; dst[1] = sm;
    }
  }
  __syncthreads();

  int dg = t & 31, strip = t >> 5, jb = strip*8;
  float4 pv[8];
  #pragma unroll
  for (int q = 0; q < 8; q++) pv[q] = *(const float4*)&tile[(jb+q)*133 + dg*4];
  float4 acc[NH];
  #pragma unroll
  for (int h = 0; h < NH; h++) acc[h] = make_float4(0.f,0.f,0.f,0.f);
  #pragma unroll
  for (int h = 0; h < NH; h++) {
    float4 w0 = *(const float4*)&wt[h*TJC + jb];
    float4 w1 = *(const float4*)&wt[h*TJC + jb + 4];
    float wq[8] = {w0.x,w0.y,w0.z,w0.w,w1.x,w1.y,w1.z,w1.w};
    float4 a = acc[h];
    #pragma unroll
    for (int q = 0; q < 8; q++) {
      a.x = fmaf(wq[q], pv[q].x, a.x);
      a.y = fmaf(wq[q], pv[q].y, a.y);
      a.z = fmaf(wq[q], pv[q].z, a.z);
      a.w = fmaf(wq[q], pv[q].w, a.w);
    }
    acc[h] = a;
  }
  __syncthreads();

  float4* red4 = (float4*)tile;
  float4 tot[2];
  tot[0] = make_float4(0.f,0.f,0.f,0.f);
  tot[1] = make_float4(0.f,0.f,0.f,0.f);
  #pragma unroll
  for (int half = 0; half < 2; half++) {
    if ((strip >> 2) == half) {
      #pragma unroll
      for (int h = 0; h < NH; h++)
        red4[(((strip & 3)*NH) + h)*32 + dg] = acc[h];
    }
    __syncthreads();
    for (int e = t, u = 0; e < NH*32; e += 256, u++) {
      int rh = e >> 5, rd = e & 31;
      #pragma unroll
      for (int s4 = 0; s4 < 4; s4++) {
        float4 v = red4[((s4*NH) + rh)*32 + rd];
        tot[u].x += v.x; tot[u].y += v.y; tot[u].z += v.z; tot[u].w += v.w;
      }
    }
    __syncthreads();
  }
  for (int e = t, u = 0; e < NH*32; e += 256, u++) {
    int rh = e >> 5, rd = e & 31;
    *(float4*)&pairpart[(((size_t)i*NC + c)*NH + rh)*DPAIR + rd*4] = tot[u];
  }
}

// ---------------------------------------------------------------- scs + pair_out combine + normalized bf16 attn matrix
__global__ __launch_bounds__(384) void k_scs_pairout(
    const float* __restrict__ msum, const float* __restrict__ pairpart,
    const float* __restrict__ S,
    u16* __restrict__ Awh, u16* __restrict__ Awl,
    u16* __restrict__ combh, u16* __restrict__ combl) {
  __shared__ float scs[NH*NC];
  int i = blockIdx.x, t = threadIdx.x;
  if (t < NH) {
    float m = -3.0e38f;
    float mc[NC], sc_[NC];
    #pragma unroll
    for (int c = 0; c < NC; c++) {
      const float* p = msum + (((size_t)i*NC + c)*NH + t)*2;
      mc[c] = p[0]; sc_[c] = p[1];
      m = fmaxf(m, mc[c]);
    }
    float s = 0.f;
    #pragma unroll
    for (int c = 0; c < NC; c++) s += sc_[c] * __expf(mc[c] - m);
    float inv = 1.f / s;
    #pragma unroll
    for (int c = 0; c < NC; c++)
      scs[t*NC + c] = __expf(mc[c] - m) * inv;
  }
  __syncthreads();
  // pair_out combine -> comb cols 768..2304 (split-bf16)
  int h = t >> 5, d = t & 31;
  float4 tot = make_float4(0.f,0.f,0.f,0.f);
  #pragma unroll
  for (int c = 0; c < NC; c++) {
    float sc = scs[h*NC + c];
    float4 v = *(const float4*)&pairpart[(((size_t)i*NC + c)*NH + h)*DPAIR + d*4];
    tot.x = fmaf(v.x, sc, tot.x); tot.y = fmaf(v.y, sc, tot.y);
    tot.z = fmaf(v.z, sc, tot.z); tot.w = fmaf(v.w, sc, tot.w);
  }
  size_t cb = (size_t)i*2304 + 768 + h*DPAIR + d*4;
  u16 h_, l_;
  split_bf16(tot.x, h_, l_); combh[cb+0] = h_; combl[cb+0] = l_;
  split_bf16(tot.y, h_, l_); combh[cb+1] = h_; combl[cb+1] = l_;
  split_bf16(tot.z, h_, l_); combh[cb+2] = h_; combl[cb+2] = l_;
  split_bf16(tot.w, h_, l_); combh[cb+3] = h_; combl[cb+3] = l_;
  // normalized attention weights -> split-bf16 Aw[h][i][j]
  for (int e = t; e < NH*LQ; e += 384) {
    int hh2 = e >> 9, j = e & 511;
    float w = S[((size_t)hh2*LQ + i)*LQ + j] * scs[hh2*NC + (j >> 6)];
    split_bf16(w, h_, l_);
    Awh[((size_t)hh2*LQ + i)*LQ + j] = h_;
    Awl[((size_t)hh2*LQ + i)*LQ + j] = l_;
  }
}

// ---------------------------------------------------------------- attn @ [v|vg] via MFMA, split-K=4 -> psum
__global__ __launch_bounds__(256) void k_attn_mfma(
    const u16* __restrict__ Awh, const u16* __restrict__ Awl,
    const u16* __restrict__ Vth, const u16* __restrict__ Vtl,
    float* __restrict__ psum) {
  int t = threadIdx.x;
  int lane = t & 63, wave = t >> 6;
  int wr = wave >> 1, wc = wave & 1;
  int z = blockIdx.x;                 // split-K
  int i0 = blockIdx.y * 64 + wr * 32;
  int h = blockIdx.z;
  int n0 = wc * 32;
  int lr = lane & 15, lk = (lane >> 4) << 3;
  size_t kb = (size_t)z*128 + lk;

  const u16* a0h = Awh + ((size_t)h*LQ + i0 + lr)*LQ + kb;
  const u16* a1h = a0h + (size_t)16*LQ;
  const u16* a0l = Awl + ((size_t)h*LQ + i0 + lr)*LQ + kb;
  const u16* a1l = a0l + (size_t)16*LQ;
  const u16* b0h = Vth + ((size_t)h*64 + n0 + lr)*LQ + kb;
  const u16* b1h = b0h + (size_t)16*LQ;
  const u16* b0l = Vtl + ((size_t)h*64 + n0 + lr)*LQ + kb;
  const u16* b1l = b0l + (size_t)16*LQ;

  f32x4 c00 = {0.f,0.f,0.f,0.f}, c01 = c00, c10 = c00, c11 = c00;
  #pragma unroll
  for (int k = 0; k < 128; k += 32) {
    bf16x8 A0h = *(const bf16x8*)(a0h + k);
    bf16x8 A1h = *(const bf16x8*)(a1h + k);
    bf16x8 B0h = *(const bf16x8*)(b0h + k);
    bf16x8 B1h = *(const bf16x8*)(b1h + k);
    bf16x8 A0l = *(const bf16x8*)(a0l + k);
    bf16x8 A1l = *(const bf16x8*)(a1l + k);
    bf16x8 B0l = *(const bf16x8*)(b0l + k);
    bf16x8 B1l = *(const bf16x8*)(b1l + k);
    c00 = __builtin_amdgcn_mfma_f32_16x16x32_bf16(A0h, B0h, c00, 0, 0, 0);
    c01 = __builtin_amdgcn_mfma_f32_16x16x32_bf16(A0h, B1h, c01, 0, 0, 0);
    c10 = __builtin_amdgcn_mfma_f32_16x16x32_bf16(A1h, B0h, c10, 0, 0, 0);
    c11 = __builtin_amdgcn_mfma_f32_16x16x32_bf16(A1h, B1h, c11, 0, 0, 0);
    c00 = __builtin_amdgcn_mfma_f32_16x16x32_bf16(A0h, B0l, c00, 0, 0, 0);
    c01 = __builtin_amdgcn_mfma_f32_16x16x32_bf16(A0h, B1l, c01, 0, 0, 0);
    c10 = __builtin_amdgcn_mfma_f32_16x16x32_bf16(A1h, B0l, c10, 0, 0, 0);
    c11 = __builtin_amdgcn_mfma_f32_16x16x32_bf16(A1h, B1l, c11, 0, 0, 0);
    c00 = __builtin_amdgcn_mfma_f32_16x16x32_bf16(A0l, B0h, c00, 0, 0, 0);
    c01 = __builtin_amdgcn_mfma_f32_16x16x32_bf16(A0l, B1h, c01, 0, 0, 0);
    c10 = __builtin_amdgcn_mfma_f32_16x16x32_bf16(A1l, B0h, c10, 0, 0, 0);
    c11 = __builtin_amdgcn_mfma_f32_16x16x32_bf16(A1l, B1h, c11, 0, 0, 0);
  }

  int orow = (lane >> 4) << 2;
  int col0 = n0 + lr, col1 = n0 + 16 + lr;
  #pragma unroll
  for (int r = 0; r < 4; r++) {
    int row0 = i0 + orow + r, row1 = row0 + 16;
    psum[(((size_t)z*LQ + row0)*NH + h)*64 + col0] = c00[r];
    psum[(((size_t)z*LQ + row0)*NH + h)*64 + col1] = c01[r];
    psum[(((size_t)z*LQ + row1)*NH + h)*64 + col0] = c10[r];
    psum[(((size_t)z*LQ + row1)*NH + h)*64 + col1] = c11[r];
  }
}

// ---------------------------------------------------------------- fused av_reduce + pts_feat -> comb (split-bf16)
__global__ void k_avpts(const float* __restrict__ psum, const float* __restrict__ rot,
                        const float* __restrict__ trans,
                        u16* __restrict__ combh, u16* __restrict__ combl) {
  int idx = blockIdx.x * 256 + threadIdx.x;
  if (idx >= LQ*NH*40) return;
  int w = idx % 40; int ih = idx / 40; int h = ih % NH; int i = ih / NH;
  size_t base = ((size_t)i*NH + h)*64;
  u16 h_, l_;
  if (w < 32) {
    float s = 0.f;
    for (int z = 0; z < 4; z++) s += psum[(size_t)z*LQ*NH*64 + base + w];
    split_bf16(s, h_, l_);
    combh[(size_t)i*2304 + h*32 + w] = h_;
    combl[(size_t)i*2304 + h*32 + w] = l_;
  } else {
    int p = w - 32;
    float g[3];
    #pragma unroll
    for (int r = 0; r < 3; r++) {
      int n = 32 + p*3 + r;
      float s = 0.f;
      for (int z = 0; z < 4; z++) s += psum[(size_t)z*LQ*NH*64 + base + n];
      g[r] = s;
    }
    const float* R = rot + (size_t)i*9;
    const float* tr = trans + (size_t)i*3;
    float x = g[0]-tr[0], y = g[1]-tr[1], z = g[2]-tr[2];
    float lx = fmaf(R[0],x, fmaf(R[3],y, R[6]*z));
    float ly = fmaf(R[1],x, fmaf(R[4],y, R[7]*z));
    float lz = fmaf(R[2],x, fmaf(R[5],y, R[8]*z));
    float nrm = sqrtf(fmaf(lx,lx, fmaf(ly,ly, lz*lz)));
    size_t dst = (size_t)i*2304 + 384 + (h*8 + p)*4;
    split_bf16(nrm, h_, l_); combh[dst+0] = h_; combl[dst+0] = l_;
    split_bf16(lx,  h_, l_); combh[dst+1] = h_; combl[dst+1] = l_;
    split_bf16(ly,  h_, l_); combh[dst+2] = h_; combl[dst+2] = l_;
    split_bf16(lz,  h_, l_); combh[dst+3] = h_; combl[dst+3] = l_;
  }
}

// ================================================================ launcher
extern "C" void kernel_launch(void* const* d_in, const int* in_sizes, int n_in,
                              void* d_out, int out_size, void* d_ws, size_t ws_size,
                              hipStream_t stream) {
  const float* single = (const float*)d_in[0];
  const float* pair   = (const float*)d_in[1];
  const float* rot    = (const float*)d_in[2];
  const float* trans  = (const float*)d_in[3];
  const float* mask   = (const float*)d_in[4];
  const float* ln_w   = (const float*)d_in[5];
  const float* ln_b   = (const float*)d_in[6];
  const float* Wq     = (const float*)d_in[7];
  const float* bq     = (const float*)d_in[8];
  const float* Wk     = (const float*)d_in[9];
  const float* bk     = (const float*)d_in[10];
  const float* Wv     = (const float*)d_in[11];
  const float* bv     = (const float*)d_in[12];
  const float* Wqp    = (const float*)d_in[13];
  const float* bqp    = (const float*)d_in[14];
  const float* Wkp    = (const float*)d_in[15];
  const float* bkp    = (const float*)d_in[16];
  const float* Wvp    = (const float*)d_in[17];
  const float* bvp    = (const float*)d_in[18];
  const float* Wpb    = (const float*)d_in[19];
  const float* bpb    = (const float*)d_in[20];
  const float* Wo     = (const float*)d_in[21];
  const float* bo     = (const float*)d_in[22];
  const float* w_c    = (const float*)d_in[23];
  const float* w_l    = (const float*)d_in[24];
  const float* gamma  = (const float*)d_in[25];
  float* out = (float*)d_out;

  float* p = (float*)d_ws;
  auto alloc = [&](size_t n) { float* r = p; p += n; return r; };
  // bf16 buffers in float units (2 u16 per float); all sizes %4==0 -> 16B alignment
  u16* WcatTh = (u16*)alloc((size_t)NPP*DS/2);
  u16* WcatTl = (u16*)alloc((size_t)NPP*DS/2);
  u16* snh    = (u16*)alloc((size_t)LQ*DS/2);
  u16* snl    = (u16*)alloc((size_t)LQ*DS/2);
  u16* WoTh   = (u16*)alloc((size_t)DS*2304/2);
  u16* WoTl   = (u16*)alloc((size_t)DS*2304/2);
  u16* combh  = (u16*)alloc((size_t)LQ*2304/2);
  u16* combl  = (u16*)alloc((size_t)LQ*2304/2);
  u16* Afh    = (u16*)alloc((size_t)NH*LQ*FE2/2);
  u16* Afl    = (u16*)alloc((size_t)NH*LQ*FE2/2);
  u16* Bfh    = (u16*)alloc((size_t)NH*LQ*FE2/2);
  u16* Bfl    = (u16*)alloc((size_t)NH*LQ*FE2/2);
  u16* Vth    = (u16*)alloc((size_t)NH*64*LQ/2);
  u16* Vtl    = (u16*)alloc((size_t)NH*64*LQ/2);
  u16* Awh    = (u16*)alloc((size_t)NH*LQ*LQ/2);
  u16* Awl    = (u16*)alloc((size_t)NH*LQ*LQ/2);
  float* bcat    = alloc(NPP);
  float* WpbT    = alloc((size_t)NH*DPAIR);
  float* C1      = alloc((size_t)LQ*NPP);
  float* S       = alloc((size_t)NH*LQ*LQ);
  float* pairpart= alloc((size_t)LQ*NC*NH*DPAIR);
  float* msum    = alloc((size_t)LQ*NC*NH*2);
  float* psum    = alloc((size_t)4*LQ*NH*64);
  float* outpart = alloc((size_t)8*LQ*DS);

  k_prep<<<dim3(897), 256, 0, stream>>>(
      Wq, Wk, Wv, Wqp, Wkp, Wvp, bq, bk, bv, bqp, bkp, bvp, Wpb, Wo,
      single, ln_w, ln_b, WcatTh, WcatTl, bcat, WpbT, WoTh, WoTl, snh, snl);
  k_gemm_mfma<<<dim3(NPP/64, LQ/64, 1), 256, 0, stream>>>(
      snh, snl, WcatTh, WcatTl, bcat, C1, nullptr, LQ, NPP, DS);
  k_rotfeat<<<dim3((LQ*NH + 255)/256), 256, 0, stream>>>(
      C1, rot, trans, gamma, w_c, w_l, Afh, Afl, Bfh, Bfl, Vth, Vtl);
  k_logits_mfma<<<dim3(LQ/64, LQ/64, NH), 256, 0, stream>>>(Afh, Afl, Bfh, Bfl, S);
  k_pair_chunk<<<dim3(LQ, NC), 256, 0, stream>>>(pair, WpbT, bpb, mask, S, pairpart, msum);
  k_scs_pairout<<<dim3(LQ), 384, 0, stream>>>(msum, pairpart, S, Awh, Awl, combh, combl);
  k_attn_mfma<<<dim3(4, LQ/64, NH), 256, 0, stream>>>(Awh, Awl, Vth, Vtl, psum);
  k_avpts<<<dim3((LQ*NH*40 + 255)/256), 256, 0, stream>>>(psum, rot, trans, combh, combl);
  k_gemm_mfma<<<dim3(DS/64, LQ/64, 8), 256, 0, stream>>>(
      combh, combl, WoTh, WoTl, nullptr, nullptr, outpart, LQ, DS, 2304);
  k_reduce_bias<<<dim3((LQ*DS + 255)/256), 256, 0, stream>>>(outpart, bo, out, LQ*DS, DS, 8);
}